// Round 6
// baseline (410.566 us; speedup 1.0000x reference)
//
#include <hip/hip_runtime.h>
#include <math.h>

#define N_NODES 50000
#define N_EDGES 600000
#define D 128
#define NLAYERS 3
#define BN_EPS 1e-5f
#define NBLK ((N_NODES + 255) / 256)       // 196 scan blocks
#define GBLK ((N_NODES + 63) / 64)         // 782 gemm blocks
#define NW (NLAYERS * 128 * 256)           // Wt elements

typedef short short8 __attribute__((ext_vector_type(8)));   // 8 bf16 (4 VGPRs)
typedef float f32x4 __attribute__((ext_vector_type(4)));

__device__ __forceinline__ float b2f(unsigned short u) {
    return __uint_as_float(((unsigned int)u) << 16);
}
__device__ __forceinline__ unsigned short f2b(float f) {  // RNE
    unsigned int b = __float_as_uint(f);
    return (unsigned short)((b + 0x7fffu + ((b >> 16) & 1u)) >> 16);
}

// ---------------- converts ----------------
__global__ void k_cvt_x(const float* __restrict__ x, unsigned short* __restrict__ xb) {
    int idx = blockIdx.x * 256 + threadIdx.x;       // float4 granule
    if (idx >= N_NODES * D / 4) return;
    float4 v = ((const float4*)x)[idx];
    ushort4 o;
    o.x = f2b(v.x); o.y = f2b(v.y); o.z = f2b(v.z); o.w = f2b(v.w);
    ((ushort4*)xb)[idx] = o;
}

// Wt[l][c][k]: k<128 -> Wl[l][k][c], k>=128 -> Wr[l][k-128][c];  W1t[c][k] = W1[k][c]
__global__ void k_cvt_weights(const float* __restrict__ Wl, const float* __restrict__ Wr,
                              const float* __restrict__ W1, unsigned short* __restrict__ Wt,
                              unsigned short* __restrict__ W1t) {
    int idx = blockIdx.x * 256 + threadIdx.x;
    if (idx < NW) {
        int l = idx >> 15;
        int rem = idx & 32767;
        int c = rem >> 8;
        int k = rem & 255;
        float v = (k < 128) ? Wl[l * 16384 + k * 128 + c]
                            : Wr[l * 16384 + (k - 128) * 128 + c];
        Wt[idx] = f2b(v);
    } else {
        int i = idx - NW;
        if (i < 64 * 128) {
            int c = i >> 7;
            int k = i & 127;
            W1t[i] = f2b(W1[k * 64 + c]);
        }
    }
}

// ---------------- CSR build ----------------
__global__ void k_hist(const int* __restrict__ dst, int* __restrict__ cnt) {
    int e = blockIdx.x * blockDim.x + threadIdx.x;
    if (e < N_EDGES) atomicAdd(&cnt[dst[e]], 1);
}

__global__ void k_local_scan(const int* __restrict__ cnt, int* __restrict__ row_ptr,
                             int* __restrict__ bsum) {
    __shared__ int sm[256];
    int tid = threadIdx.x;
    int i = blockIdx.x * 256 + tid;
    int v = (i < N_NODES) ? cnt[i] : 0;
    sm[tid] = v;
    __syncthreads();
    for (int off = 1; off < 256; off <<= 1) {
        int t = (tid >= off) ? sm[tid - off] : 0;
        __syncthreads();
        sm[tid] += t;
        __syncthreads();
    }
    int incl = sm[tid];
    if (i < N_NODES) row_ptr[i] = incl - v;
    if (tid == 255) bsum[blockIdx.x] = incl;
}

__global__ void k_scan_bsums(const int* __restrict__ bsum, int* __restrict__ boff,
                             int* __restrict__ row_ptr) {
    __shared__ int sm[256];
    int tid = threadIdx.x;
    int v = (tid < NBLK) ? bsum[tid] : 0;
    sm[tid] = v;
    __syncthreads();
    for (int off = 1; off < 256; off <<= 1) {
        int t = (tid >= off) ? sm[tid - off] : 0;
        __syncthreads();
        sm[tid] += t;
        __syncthreads();
    }
    int incl = sm[tid];
    if (tid < NBLK) boff[tid] = incl - v;
    if (tid == 255) row_ptr[N_NODES] = incl;
}

__global__ void k_add_off(int* __restrict__ row_ptr, const int* __restrict__ boff,
                          int* __restrict__ row_fill) {
    int i = blockIdx.x * 256 + threadIdx.x;
    if (i < N_NODES) {
        int v = row_ptr[i] + boff[i >> 8];
        row_ptr[i] = v;
        row_fill[i] = v;
    }
}

__global__ void k_fill(const int* __restrict__ src, const int* __restrict__ dst,
                       int* __restrict__ row_fill, int* __restrict__ edge_sorted) {
    int e = blockIdx.x * blockDim.x + threadIdx.x;
    if (e < N_EDGES) {
        int pos = atomicAdd(&row_fill[dst[e]], 1);
        edge_sorted[pos] = src[e];
    }
}

// ---------------- mean aggregation: ONE WAVE PER NODE ----------------
// lanes = 4 edge-slots x 16 row-chunks(16B); 8 edges in flight per iteration;
// cross-slot combine via shfl_xor(16/32). No intra-wave loop divergence.
__global__ __launch_bounds__(256) void k_agg(const unsigned short* __restrict__ h,
                                             const int* __restrict__ edge_sorted,
                                             const int* __restrict__ row_ptr,
                                             unsigned short* __restrict__ meanbuf) {
    int node = blockIdx.x * 4 + (threadIdx.x >> 6);
    if (node >= N_NODES) return;
    int lane  = threadIdx.x & 63;
    int eslot = lane >> 4;      // 0..3: which edge in the group of 4
    int c16   = lane & 15;      // 16B chunk of the 256B row
    int beg = row_ptr[node], end = row_ptr[node + 1];
    int deg = end - beg;
    const short8* hp = (const short8*)h;
    float a[8];
#pragma unroll
    for (int i = 0; i < 8; ++i) a[i] = 0.f;
    int e1 = end - 1;
    for (int base = beg; base < end; base += 8) {
        int j0 = base + eslot;
        int j1 = j0 + 4;
        int i0 = (j0 <= e1) ? j0 : e1;
        int i1 = (j1 <= e1) ? j1 : e1;
        int s0 = edge_sorted[i0];
        int s1 = edge_sorted[i1];
        short8 v0 = hp[(size_t)s0 * 16 + c16];
        short8 v1 = hp[(size_t)s1 * 16 + c16];
        float m0 = (j0 < end) ? 1.f : 0.f;
        float m1 = (j1 < end) ? 1.f : 0.f;
#pragma unroll
        for (int i = 0; i < 8; ++i) {
            float t = fmaf(m0, b2f((unsigned short)v0[i]), a[i]);
            a[i] = fmaf(m1, b2f((unsigned short)v1[i]), t);
        }
    }
#pragma unroll
    for (int i = 0; i < 8; ++i) {
        a[i] += __shfl_xor(a[i], 16);
        a[i] += __shfl_xor(a[i], 32);
    }
    if (eslot == 0) {
        float inv = 1.0f / fmaxf((float)deg, 1.0f);
        short8 o;
#pragma unroll
        for (int i = 0; i < 8; ++i) o[i] = (short)f2b(a[i] * inv);
        ((short8*)meanbuf)[(size_t)node * 16 + c16] = o;
    }
}

// ---------------- bf16 MFMA GEMM + atomic BN stats ----------------
// pre[n][j] = sum_k mean[n][k]*Wl[k][j] + h[n][k]*Wr[k][j] + bias[j]  (fp32 out)
__global__ __launch_bounds__(256) void k_gemm_mfma(const unsigned short* __restrict__ Am,
                                                   const unsigned short* __restrict__ Ah,
                                                   const unsigned short* __restrict__ Wt,
                                                   const float* __restrict__ bias,
                                                   float* __restrict__ pre,
                                                   float* __restrict__ sums) {
    __shared__ float red[4][256];
    int tid = threadIdx.x;
    int wave = tid >> 6;
    int lane = tid & 63;
    int col = lane & 15;
    int quad = lane >> 4;
    int row_base = blockIdx.x * 64 + wave * 16;
    bool valid = row_base < N_NODES;       // N % 16 == 0 -> all-or-nothing per wave

    f32x4 acc[8];
#pragma unroll
    for (int t = 0; t < 8; ++t) acc[t] = (f32x4){0.f, 0.f, 0.f, 0.f};

    if (valid) {
        int arow = row_base + col;
#pragma unroll
        for (int kk = 0; kk < 8; ++kk) {
            const unsigned short* Aptr = (kk < 4) ? Am : Ah;
            int kofs = (kk & 3) * 32 + quad * 8;
            short8 a = *(const short8*)(Aptr + (size_t)arow * D + kofs);
#pragma unroll
            for (int t = 0; t < 8; ++t) {
                short8 b = *(const short8*)(Wt + (size_t)(t * 16 + col) * 256 + kk * 32 + quad * 8);
                acc[t] = __builtin_amdgcn_mfma_f32_16x16x32_bf16(a, b, acc[t], 0, 0, 0);
            }
        }
    }

#pragma unroll
    for (int t = 0; t < 8; ++t) {
        float s = 0.f, ss = 0.f;
        if (valid) {
            float bc = bias[t * 16 + col];
#pragma unroll
            for (int r = 0; r < 4; ++r) {
                float v = acc[t][r] + bc;
                pre[(size_t)(row_base + quad * 4 + r) * D + t * 16 + col] = v;
                s += v;
                ss += v * v;
            }
        }
        s += __shfl_xor(s, 16);  ss += __shfl_xor(ss, 16);
        s += __shfl_xor(s, 32);  ss += __shfl_xor(ss, 32);
        if (quad == 0) {
            red[wave][t * 16 + col] = s;
            red[wave][128 + t * 16 + col] = ss;
        }
    }
    __syncthreads();
    float pv = red[0][tid] + red[1][tid] + red[2][tid] + red[3][tid];
    atomicAdd(&sums[tid], pv);
}

// ---------------- BN apply + ReLU: fp32 pre -> bf16 h ----------------
__global__ void k_bnrelu(const float* __restrict__ pre, const float* __restrict__ sums,
                         const float* __restrict__ gamma, const float* __restrict__ beta,
                         unsigned short* __restrict__ outbuf) {
    int idx = blockIdx.x * blockDim.x + threadIdx.x;
    const int total = N_NODES * D / 4;
    if (idx >= total) return;
    const float* sumsq = sums + 128;
    int col4 = (idx & 31) * 4;
    float4 v = ((const float4*)pre)[idx];
    float vv[4] = {v.x, v.y, v.z, v.w};
    unsigned short o[4];
    const float invN = 1.0f / (float)N_NODES;
#pragma unroll
    for (int c = 0; c < 4; ++c) {
        int j = col4 + c;
        float mu  = sums[j] * invN;
        float var = sumsq[j] * invN - mu * mu;
        float sc = gamma[j] * rsqrtf(var + BN_EPS);
        float sh = beta[j] - mu * sc;
        float x = vv[c] * sc + sh;
        o[c] = f2b(fmaxf(x, 0.f));
    }
    ushort4 ov; ov.x = o[0]; ov.y = o[1]; ov.z = o[2]; ov.w = o[3];
    ((ushort4*)outbuf)[idx] = ov;
}

// ---------------- fused MLP head + softmax via MFMA: wave -> 16 nodes ----------------
__global__ __launch_bounds__(256) void k_mlp_mfma(const unsigned short* __restrict__ h,
                                                  const unsigned short* __restrict__ W1t,
                                                  const float* __restrict__ b1,
                                                  const float* __restrict__ W2,
                                                  const float* __restrict__ b2,
                                                  float* __restrict__ out) {
    int wave = threadIdx.x >> 6;
    int lane = threadIdx.x & 63;
    int col = lane & 15;
    int quad = lane >> 4;
    int row_base = blockIdx.x * 64 + wave * 16;
    if (row_base >= N_NODES) return;       // N % 16 == 0 -> all-or-nothing per wave
    int arow = row_base + col;

    f32x4 acc[4];
#pragma unroll
    for (int t = 0; t < 4; ++t) acc[t] = (f32x4){0.f, 0.f, 0.f, 0.f};

#pragma unroll
    for (int kk = 0; kk < 4; ++kk) {
        short8 a = *(const short8*)(h + (size_t)arow * D + kk * 32 + quad * 8);
#pragma unroll
        for (int t = 0; t < 4; ++t) {
            short8 b = *(const short8*)(W1t + (size_t)(t * 16 + col) * 128 + kk * 32 + quad * 8);
            acc[t] = __builtin_amdgcn_mfma_f32_16x16x32_bf16(a, b, acc[t], 0, 0, 0);
        }
    }

    float pa[4] = {0.f, 0.f, 0.f, 0.f}, pb[4] = {0.f, 0.f, 0.f, 0.f};
#pragma unroll
    for (int t = 0; t < 4; ++t) {
        int c = t * 16 + col;
        float bb = b1[c];
        float w2a = W2[c * 2], w2b = W2[c * 2 + 1];
#pragma unroll
        for (int r = 0; r < 4; ++r) {
            float z = fmaxf(acc[t][r] + bb, 0.f);
            pa[r] = fmaf(z, w2a, pa[r]);
            pb[r] = fmaf(z, w2b, pb[r]);
        }
    }
#pragma unroll
    for (int m = 1; m < 16; m <<= 1) {
#pragma unroll
        for (int r = 0; r < 4; ++r) {
            pa[r] += __shfl_xor(pa[r], m);
            pb[r] += __shfl_xor(pb[r], m);
        }
    }
    if (col < 4) {
        int node = row_base + quad * 4 + col;
        float l0 = pa[col] + b2[0], l1 = pb[col] + b2[1];
        float2 lg; lg.x = l0; lg.y = l1;
        ((float2*)out)[node] = lg;
        float m = fmaxf(l0, l1);
        float e0 = expf(l0 - m), e1 = expf(l1 - m);
        float s = 1.0f / (e0 + e1);
        float2 pr; pr.x = e0 * s; pr.y = e1 * s;
        ((float2*)(out + 2 * N_NODES))[node] = pr;
    }
}

extern "C" void kernel_launch(void* const* d_in, const int* in_sizes, int n_in,
                              void* d_out, int out_size, void* d_ws, size_t ws_size,
                              hipStream_t stream) {
    const float* x     = (const float*)d_in[0];
    const int*   ei    = (const int*)d_in[1];
    const int*   src   = ei;
    const int*   dst   = ei + N_EDGES;
    const float* Wl    = (const float*)d_in[2];
    const float* Wr    = (const float*)d_in[3];
    const float* bl    = (const float*)d_in[4];
    const float* gamma = (const float*)d_in[5];
    const float* beta  = (const float*)d_in[6];
    const float* W1    = (const float*)d_in[7];
    const float* b1    = (const float*)d_in[8];
    const float* W2    = (const float*)d_in[9];
    const float* b2    = (const float*)d_in[10];
    float* out = (float*)d_out;

    char* ws = (char*)d_ws;
    size_t off = 0;
    auto alloc = [&](size_t bytes) -> void* {
        void* p = ws + off;
        off += (bytes + 255) & ~(size_t)255;
        return p;
    };
    unsigned short* xb   = (unsigned short*)alloc((size_t)N_NODES * D * 2);  // reused as 2nd h buf
    unsigned short* Ha   = (unsigned short*)alloc((size_t)N_NODES * D * 2);
    unsigned short* Mb   = (unsigned short*)alloc((size_t)N_NODES * D * 2);
    float* pre           = (float*)alloc((size_t)N_NODES * D * 4);
    unsigned short* Wtb  = (unsigned short*)alloc((size_t)NW * 2);
    unsigned short* W1t  = (unsigned short*)alloc((size_t)64 * 128 * 2);
    int* cnt             = (int*)alloc((size_t)N_NODES * 4);
    int* row_ptr         = (int*)alloc((size_t)(N_NODES + 1) * 4);
    int* row_fill        = (int*)alloc((size_t)N_NODES * 4);
    int* edge_sorted     = (int*)alloc((size_t)N_EDGES * 4);
    int* bsum            = (int*)alloc((size_t)NBLK * 4);
    int* boff            = (int*)alloc((size_t)NBLK * 4);
    float* sums_all      = (float*)alloc(NLAYERS * 256 * 4);  // per-layer [sums|sumsq]

    // --- converts ---
    k_cvt_x<<<(N_NODES * D / 4 + 255) / 256, 256, 0, stream>>>(x, xb);
    k_cvt_weights<<<(NW + 64 * 128 + 255) / 256, 256, 0, stream>>>(Wl, Wr, W1, Wtb, W1t);

    // --- build CSR (by dst), reused across the 3 layers ---
    hipMemsetAsync(cnt, 0, (size_t)N_NODES * 4, stream);
    k_hist<<<(N_EDGES + 255) / 256, 256, 0, stream>>>(dst, cnt);
    k_local_scan<<<NBLK, 256, 0, stream>>>(cnt, row_ptr, bsum);
    k_scan_bsums<<<1, 256, 0, stream>>>(bsum, boff, row_ptr);
    k_add_off<<<NBLK, 256, 0, stream>>>(row_ptr, boff, row_fill);
    k_fill<<<(N_EDGES + 255) / 256, 256, 0, stream>>>(src, dst, row_fill, edge_sorted);

    // zero all per-layer BN stat slots once
    hipMemsetAsync(sums_all, 0, NLAYERS * 256 * 4, stream);

    // --- 3 SAGE layers (h buffers ping-pong: xb -> Ha -> xb -> Ha) ---
    const unsigned short* hcur = xb;
    unsigned short* hout[3] = {Ha, xb, Ha};
    for (int l = 0; l < NLAYERS; ++l) {
        float* sums = sums_all + l * 256;
        k_agg<<<(N_NODES + 3) / 4, 256, 0, stream>>>(hcur, edge_sorted, row_ptr, Mb);
        k_gemm_mfma<<<GBLK, 256, 0, stream>>>(Mb, hcur, Wtb + (size_t)l * 32768,
                                              bl + l * D, pre, sums);
        k_bnrelu<<<(N_NODES * D / 4 + 255) / 256, 256, 0, stream>>>(
            pre, sums, gamma + l * D, beta + l * D, hout[l]);
        hcur = hout[l];
    }

    // --- fused MLP head + softmax ---
    k_mlp_mfma<<<GBLK, 256, 0, stream>>>(hcur, W1t, b1, W2, b2, out);
}